// Round 5
// baseline (870.035 us; speedup 1.0000x reference)
//
#include <hip/hip_runtime.h>
#include <hip/hip_fp16.h>

#define DD 300
#define SS 512
#define NW 16          // waves per block in main kernel
#define NF4 75         // float4 per 300-float row
#define VV 50000

// Workspace layout (float index):
//   0: c_k   1: c_q(raw)   2: c_qs = c_q + dot(uq, bx)
//   16..316    : u    = wk @ Wk
//   320..620   : uq   = wq @ Wq
//   640..940   : bc   = Wp @ bk + bp
//   1024..91024    : WcT  [e*300+i] = (Wp@Wk)[i,e]
//   92160..182160  : WxT  [e*300+i] = Wx[i,e]
//   183296..183596 : uqWx [j] = sum_i uq[i]*Wx[i,j]
//   184320..234320 : eu[v] = dot(emb[v], u)
//   235520..       : emb16 (50000 x 300 half, ushort4[75]/row)
#define WCT_OFF  1024
#define WXT_OFF  92160
#define UQWX_OFF 183296
#define EU_OFF   184320
#define E16_OFF  235520

#define FMA4(acc, s, v) { acc.x += (s)*(v).x; acc.y += (s)*(v).y; \
                          acc.z += (s)*(v).z; acc.w += (s)*(v).w; }

// fast tanh/exp: t = e^{2z}; tanh = 1 - 2/(t+1); p = e^{tanh}
__device__ __forceinline__ float fast_exp_tanh(float z) {
    const float t = __expf(2.0f * z);
    const float th = 1.0f - 2.0f / (t + 1.0f);
    return __expf(th);
}

// ---------------------------------------------------------------------------
// K1: weight-side precompute. 102 blocks x 1024 threads.
//   blocks 0..99 : WcT columns for output rows 3b..3b+2 (scattered stores)
//   block 100    : u = wk@Wk, c_k
//   block 101    : uq = wq@Wq, c_q, bc = Wp@bk + bp
// ---------------------------------------------------------------------------
__global__ __launch_bounds__(1024) void precompute(
    const float* __restrict__ Wk, const float* __restrict__ bk,
    const float* __restrict__ Wq, const float* __restrict__ bq,
    const float* __restrict__ w_mlp,
    const float* __restrict__ Wp, const float* __restrict__ bp,
    float* __restrict__ ws)
{
    const int blk  = blockIdx.x;
    const int tid  = threadIdx.x;
    const int wv   = tid >> 6;
    const int lane = tid & 63;
    __shared__ __align__(16) float buf[16 * 304 * 3 + 3 * 304];  // 62 KB
    __shared__ float red[16];

    if (blk < 100) {
        const int i0 = blk * 3;
        float* sWp = buf + 16 * 304 * 3;          // [3][304]
        for (int r = tid; r < 3 * DD; r += 1024)
            sWp[(r / DD) * 304 + (r % DD)] = Wp[i0 * DD + r];
        __syncthreads();

        float4 a00{0,0,0,0}, a01{0,0,0,0}, a10{0,0,0,0},
               a11{0,0,0,0}, a20{0,0,0,0}, a21{0,0,0,0};
        for (int e = wv; e < DD; e += NW) {
            const float4* kr = (const float4*)(Wk + e * DD);
            const float4 k0 = kr[lane];
            const float p0 = sWp[e], p1 = sWp[304 + e], p2 = sWp[608 + e];
            FMA4(a00, p0, k0); FMA4(a10, p1, k0); FMA4(a20, p2, k0);
            if (lane < 11) {
                const float4 k1 = kr[64 + lane];
                FMA4(a01, p0, k1); FMA4(a11, p1, k1); FMA4(a21, p2, k1);
            }
        }
        float4* p0r = (float4*)(buf + (wv * 3 + 0) * 304);
        float4* p1r = (float4*)(buf + (wv * 3 + 1) * 304);
        float4* p2r = (float4*)(buf + (wv * 3 + 2) * 304);
        p0r[lane] = a00; p1r[lane] = a10; p2r[lane] = a20;
        if (lane < 11) { p0r[64+lane] = a01; p1r[64+lane] = a11; p2r[64+lane] = a21; }
        __syncthreads();
        if (tid < DD) {
            #pragma unroll
            for (int r = 0; r < 3; ++r) {
                float s = 0.f;
                for (int w = 0; w < NW; ++w) s += buf[(w * 3 + r) * 304 + tid];
                // transposed store: WcT[e=tid][i=i0+r]
                ws[WCT_OFF + tid * DD + i0 + r] = s;
            }
        }
        return;
    }

    const float* M  = (blk == 100) ? Wk : Wq;
    const float* vw = (blk == 100) ? w_mlp : (w_mlp + DD);
    float* s_w = buf + 16 * 304;
    float* s_b = buf + 16 * 304 + 304;
    if (tid < DD) {
        s_w[tid] = vw[tid];
        if (blk == 101) s_b[tid] = bk[tid];
    }
    __syncthreads();

    float4 a0{0,0,0,0}, a1{0,0,0,0};
    for (int e = wv; e < DD; e += NW) {
        const float4* kr = (const float4*)(M + e * DD);
        const float s = s_w[e];
        const float4 k0 = kr[lane];
        FMA4(a0, s, k0);
        if (lane < 11) { const float4 k1 = kr[64 + lane]; FMA4(a1, s, k1); }
    }
    float4* pr = (float4*)(buf + wv * 304);
    pr[lane] = a0;
    if (lane < 11) pr[64 + lane] = a1;

    float pk = 0.f;
    if (tid < DD) pk = ((blk == 100) ? bk[tid] : bq[tid]) * s_w[tid];
    #pragma unroll
    for (int off = 32; off; off >>= 1) pk += __shfl_xor(pk, off);
    if (lane == 0) red[wv] = pk;
    __syncthreads();

    const int voff = (blk == 100) ? 16 : 320;
    if (tid < DD) {
        float s = 0.f;
        #pragma unroll
        for (int w = 0; w < NW; ++w) s += buf[w * 304 + tid];
        ws[voff + tid] = s;
    }
    if (tid == 0) {
        float s = 0.f;
        for (int w = 0; w < NW; ++w) s += red[w];
        ws[(blk == 100) ? 0 : 1] = s;
    }
    if (blk == 101 && tid < DD) {
        const float4* wr = (const float4*)(Wp + tid * DD);
        const float4* b4 = (const float4*)s_b;
        float a = 0.f;
        for (int j = 0; j < NF4; ++j) {
            const float4 w4 = wr[j];
            const float4 bb = b4[j];
            a += w4.x * bb.x + w4.y * bb.y + w4.z * bb.z + w4.w * bb.w;
        }
        ws[640 + tid] = a + bp[tid];
    }
}

// ---------------------------------------------------------------------------
// K1b: 100 tile-transpose blocks (Wx -> WxT) + block 100 (uqWx, c_qs).
// Runs after K1 (needs uq, c_q).
// ---------------------------------------------------------------------------
__global__ __launch_bounds__(1024) void transpose_aux(
    const float* __restrict__ Wx, const float* __restrict__ bx,
    float* __restrict__ ws)
{
    const int blk = blockIdx.x;
    const int tid = threadIdx.x;
    __shared__ __align__(16) float tile[32][33];
    __shared__ float uq_s[304];
    __shared__ float redc[16];

    if (blk < 100) {
        const int bi = blk / 10, bj = blk % 10;
        const int ty = tid >> 5, tx = tid & 31;
        const int r = bi * 32 + ty, c = bj * 32 + tx;
        if (r < DD && c < DD) tile[ty][tx] = Wx[r * DD + c];
        __syncthreads();
        const int ro = bj * 32 + ty, co = bi * 32 + tx;
        if (ro < DD && co < DD)
            ws[WXT_OFF + ro * DD + co] = tile[tx][ty];
        return;
    }

    // block 100: uqWx[j] = sum_i uq[i]*Wx[i*DD+j];  c_qs = c_q + dot(uq,bx)
    const int wv = tid >> 6, lane = tid & 63;
    if (tid < DD) uq_s[tid] = ws[320 + tid];
    __syncthreads();
    if (tid < DD) {
        const float* col = Wx + tid;
        float a0 = 0.f, a1 = 0.f, a2 = 0.f, a3 = 0.f;
        for (int i = 0; i < DD; i += 4) {
            a0 += uq_s[i]     * col[(i)     * DD];
            a1 += uq_s[i + 1] * col[(i + 1) * DD];
            a2 += uq_s[i + 2] * col[(i + 2) * DD];
            a3 += uq_s[i + 3] * col[(i + 3) * DD];
        }
        ws[UQWX_OFF + tid] = (a0 + a1) + (a2 + a3);
    }
    float pq = (tid < DD) ? uq_s[tid] * bx[tid] : 0.f;
    #pragma unroll
    for (int off = 32; off; off >>= 1) pq += __shfl_xor(pq, off);
    if (lane == 0 && wv < 5) redc[wv] = pq;
    __syncthreads();
    if (tid == 0) {
        float s = 0.f;
        for (int w = 0; w < 5; ++w) s += redc[w];
        ws[2] = ws[1] + s;
    }
}

// ---------------------------------------------------------------------------
// K2: one streaming pass over emb: eu[v] = dot(emb[v], u) + fp16 copy.
// ---------------------------------------------------------------------------
__global__ __launch_bounds__(1024) void build_tables(
    const float* __restrict__ emb, float* __restrict__ ws, const int do16)
{
    const int tid  = threadIdx.x;
    const int wv   = tid >> 6;
    const int lane = tid & 63;
    __shared__ __align__(16) float u_s[DD];
    if (tid < DD) u_s[tid] = ws[16 + tid];
    __syncthreads();

    const float4* u4 = (const float4*)u_s;
    const float4  q0 = u4[lane];
    const float4  q1 = (lane < 11) ? u4[64 + lane] : float4{0, 0, 0, 0};
    ushort4* e16 = (ushort4*)(ws + E16_OFF);

    const int gw     = blockIdx.x * (1024 / 64) + wv;
    const int stride = gridDim.x * (1024 / 64);
    for (int v = gw; v < VV; v += stride) {
        const float4* er = (const float4*)(emb + (size_t)v * DD);
        const float4 e0 = er[lane];
        float4 e1{0, 0, 0, 0};
        float a = e0.x * q0.x + e0.y * q0.y + e0.z * q0.z + e0.w * q0.w;
        if (lane < 11) {
            e1 = er[64 + lane];
            a += e1.x * q1.x + e1.y * q1.y + e1.z * q1.z + e1.w * q1.w;
        }
        #pragma unroll
        for (int off = 32; off; off >>= 1) a += __shfl_xor(a, off);
        if (lane == 0) ws[EU_OFF + v] = a;
        if (do16) {
            ushort4 h0;
            h0.x = __half_as_ushort(__float2half(e0.x));
            h0.y = __half_as_ushort(__float2half(e0.y));
            h0.z = __half_as_ushort(__float2half(e0.z));
            h0.w = __half_as_ushort(__float2half(e0.w));
            e16[(size_t)v * NF4 + lane] = h0;
            if (lane < 11) {
                ushort4 h1;
                h1.x = __half_as_ushort(__float2half(e1.x));
                h1.y = __half_as_ushort(__float2half(e1.y));
                h1.z = __half_as_ushort(__float2half(e1.z));
                h1.w = __half_as_ushort(__float2half(e1.w));
                e16[(size_t)v * NF4 + 64 + lane] = h1;
            }
        }
    }
}

// ---------------------------------------------------------------------------
// K3: main kernel. One block per batch row, 1024 threads = 16 waves.
// Matvecs: thread-per-output-column on transposed weights, no cross-lane ops.
// ---------------------------------------------------------------------------
__global__ __launch_bounds__(1024, 8) void memnet_main(
    const int* __restrict__ text, const int* __restrict__ asp,
    const float* __restrict__ emb,
    const float* __restrict__ Wd, const float* __restrict__ bd,
    const float* __restrict__ bx,
    const float* __restrict__ ws,
    float* __restrict__ out, const int use16)
{
    const int b    = blockIdx.x;
    const int tid  = threadIdx.x;
    const int wv   = tid >> 6;
    const int lane = tid & 63;
    const int g    = tid / 320;            // matvec e-group 0..2 (g==3 idle)
    const int j    = tid - g * 320;        // output column within group
    const bool mvA = (g < 3) && (j < DD);
    const int e0   = g * 100;

    __shared__ __align__(16) float ks[SS];
    __shared__ __align__(16) float cw[SS];
    __shared__ __align__(16) float wgt[SS];
    __shared__ __align__(16) int   ti[SS];
    __shared__ __align__(16) float xv[304];
    __shared__ __align__(16) float xn[304];
    __shared__ __align__(16) float mv[304];
    __shared__ __align__(16) float uqx_s[304];
    __shared__ __align__(16) float partial[3][304];
    __shared__ __align__(16) float mpart[NW][304];
    __shared__ float redq[8];
    __shared__ float red2[8];

    // ---- tokens + length ----
    int t = 0;
    if (tid < SS) { t = text[(size_t)b * SS + tid]; ti[tid] = t; }
    const unsigned long long bal = __ballot(tid < SS && t != 0);
    if (lane == 0 && wv < 8) redq[wv] = (float)__popcll(bal);
    __syncthreads();

    int len = 0;
    #pragma unroll
    for (int w = 0; w < 8; ++w) len += (int)redq[w];
    const float lenf = (float)len;
    const int   s0   = SS - len;

    const float c_k  = ws[0];
    const float c_qs = ws[2];

    if (tid < SS) {
        const int jj = tid - s0;
        const float wg = (jj >= 0) ? (1.0f - (float)jj / lenf) : 1.0f;
        wgt[tid] = wg;
        ks[tid]  = wg * ws[EU_OFF + t] + c_k;    // eu[0]==0 -> pad ks = c_k
    }

    if (tid < DD) {
        uqx_s[tid] = ws[UQWX_OFF + tid];
        float na = 0.f, a = 0.f;
        #pragma unroll
        for (int k = 0; k < 8; ++k) {
            const int idx = asp[b * 8 + k];
            na += (idx != 0) ? 1.0f : 0.0f;
            a += emb[(size_t)idx * DD + tid];
        }
        xv[tid] = a / na;
    }
    __syncthreads();

    const ushort4* e16 = (const ushort4*)(ws + E16_OFF);
    const float* WxT = ws + WXT_OFF;
    const float* WcT = ws + WCT_OFF;
    const float* bc  = ws + 640;

    // ---- hop loop ----
    for (int hop = 0; hop < 3; ++hop) {
        // phase 1: xn partials (WxT) + qs partial from xv
        if (mvA) {
            const float* col = WxT + j;
            float a0 = 0.f, a1 = 0.f, a2 = 0.f, a3 = 0.f;
            for (int e = e0; e < e0 + 100; e += 4) {
                a0 += xv[e]     * col[(e)     * DD];
                a1 += xv[e + 1] * col[(e + 1) * DD];
                a2 += xv[e + 2] * col[(e + 2) * DD];
                a3 += xv[e + 3] * col[(e + 3) * DD];
            }
            partial[g][j] = (a0 + a1) + (a2 + a3);
        }
        float qp = (tid < DD) ? uqx_s[tid] * xv[tid] : 0.f;
        #pragma unroll
        for (int off = 32; off; off >>= 1) qp += __shfl_xor(qp, off);
        if (lane == 0 && wv < 5) redq[wv] = qp;
        __syncthreads();                                   // B1

        // phase 2: qs; p/cw/sumP partials; finalize xn
        float qs = c_qs;
        #pragma unroll
        for (int w = 0; w < 5; ++w) qs += redq[w];

        float p = 0.f;
        if (tid < SS) {
            p = fast_exp_tanh(ks[tid] + qs);
            cw[tid] = p * wgt[tid];
        }
        float sp = p;
        #pragma unroll
        for (int off = 32; off; off >>= 1) sp += __shfl_xor(sp, off);
        if (lane == 0 && wv < 8) red2[wv] = sp;
        if (tid < DD)
            xn[tid] = partial[0][tid] + partial[1][tid] + partial[2][tid] + bx[tid];
        __syncthreads();                                   // B2

        float sumP = 0.f;
        #pragma unroll
        for (int w = 0; w < 8; ++w) sumP += red2[w];

        // phase 3: m-gather (fp16 table), per-wave register partials
        {
            float4 acc{0, 0, 0, 0}, accb{0, 0, 0, 0};
            const int start = s0 + ((wv - s0) & (NW - 1));
            if (use16) {
                #pragma unroll 4
                for (int s = start; s < SS; s += NW) {
                    const int row = ti[s];
                    const float c = cw[s];
                    const ushort4* r16 = e16 + (size_t)row * NF4;
                    const ushort4 h0 = r16[lane];
                    const float2 f0 = __half22float2(*(const __half2*)&h0.x);
                    const float2 f1 = __half22float2(*(const __half2*)&h0.z);
                    acc.x += c * f0.x; acc.y += c * f0.y;
                    acc.z += c * f1.x; acc.w += c * f1.y;
                    if (lane < 11) {
                        const ushort4 h1 = r16[64 + lane];
                        const float2 g0 = __half22float2(*(const __half2*)&h1.x);
                        const float2 g1 = __half22float2(*(const __half2*)&h1.z);
                        accb.x += c * g0.x; accb.y += c * g0.y;
                        accb.z += c * g1.x; accb.w += c * g1.y;
                    }
                }
            } else {
                #pragma unroll 4
                for (int s = start; s < SS; s += NW) {
                    const int row = ti[s];
                    const float c = cw[s];
                    const float4* er = (const float4*)(emb + (size_t)row * DD);
                    const float4 f = er[lane];
                    acc.x += c * f.x; acc.y += c * f.y;
                    acc.z += c * f.z; acc.w += c * f.w;
                    if (lane < 11) {
                        const float4 f1 = er[64 + lane];
                        accb.x += c * f1.x; accb.y += c * f1.y;
                        accb.z += c * f1.z; accb.w += c * f1.w;
                    }
                }
            }
            ((float4*)&mpart[wv][0])[lane] = acc;
            if (lane < 11) ((float4*)&mpart[wv][0])[64 + lane] = accb;
        }
        __syncthreads();                                   // B3

        if (tid < DD) {
            float mm = 0.f;
            #pragma unroll
            for (int w = 0; w < NW; ++w) mm += mpart[w][tid];
            mv[tid] = mm / sumP;
        }
        __syncthreads();                                   // B4

        // phase 4: xv partials (WcT)
        if (mvA) {
            const float* col = WcT + j;
            float a0 = 0.f, a1 = 0.f, a2 = 0.f, a3 = 0.f;
            for (int e = e0; e < e0 + 100; e += 4) {
                a0 += mv[e]     * col[(e)     * DD];
                a1 += mv[e + 1] * col[(e + 1) * DD];
                a2 += mv[e + 2] * col[(e + 2) * DD];
                a3 += mv[e + 3] * col[(e + 3) * DD];
            }
            partial[g][j] = (a0 + a1) + (a2 + a3);
        }
        __syncthreads();                                   // B5

        if (tid < DD)
            xv[tid] = partial[0][tid] + partial[1][tid] + partial[2][tid]
                    + bc[tid] + xn[tid];
        __syncthreads();                                   // B6
    }

    // ---- out[b,p] = dot(Wd[p], xv) + bd[p], P=3 ----
    if (wv < 3) {
        const float4* wr = (const float4*)(Wd + wv * DD);
        const float4* x4 = (const float4*)xv;
        const float4 w0 = wr[lane];
        const float4 v0 = x4[lane];
        float a = w0.x * v0.x + w0.y * v0.y + w0.z * v0.z + w0.w * v0.w;
        if (lane < 11) {
            const float4 w1 = wr[64 + lane];
            const float4 v1 = x4[64 + lane];
            a += w1.x * v1.x + w1.y * v1.y + w1.z * v1.z + w1.w * v1.w;
        }
        #pragma unroll
        for (int off = 32; off; off >>= 1) a += __shfl_xor(a, off);
        if (lane == 0) out[b * 3 + wv] = a + bd[wv];
    }
}

extern "C" void kernel_launch(void* const* d_in, const int* in_sizes, int n_in,
                              void* d_out, int out_size, void* d_ws, size_t ws_size,
                              hipStream_t stream)
{
    const int*   text = (const int*)d_in[0];
    const int*   asp  = (const int*)d_in[1];
    const float* emb  = (const float*)d_in[2];
    const float* Wx   = (const float*)d_in[3];
    const float* bx   = (const float*)d_in[4];
    const float* Wk   = (const float*)d_in[5];
    const float* bk   = (const float*)d_in[6];
    const float* Wq   = (const float*)d_in[7];
    const float* bq   = (const float*)d_in[8];
    const float* wm   = (const float*)d_in[9];
    const float* Wp   = (const float*)d_in[10];
    const float* bp   = (const float*)d_in[11];
    const float* Wd   = (const float*)d_in[12];
    const float* bd   = (const float*)d_in[13];
    float* out = (float*)d_out;
    float* ws  = (float*)d_ws;

    const size_t need = (size_t)E16_OFF * 4 + (size_t)VV * DD * 2;
    const int use16 = (ws_size >= need) ? 1 : 0;

    precompute<<<102, 1024, 0, stream>>>(Wk, bk, Wq, bq, wm, Wp, bp, ws);
    transpose_aux<<<101, 1024, 0, stream>>>(Wx, bx, ws);
    build_tables<<<512, 1024, 0, stream>>>(emb, ws, use16);
    memnet_main<<<512, 1024, 0, stream>>>(text, asp, emb, Wd, bd, bx, ws, out, use16);
}

// Round 6
// 381.796 us; speedup vs baseline: 2.2788x; 2.2788x over previous
//
#include <hip/hip_runtime.h>
#include <hip/hip_fp16.h>

#define DD 300
#define SS 512
#define VV 50000
#define NF4 75

// Workspace layout (float index):
#define CK       0        // c_k = dot(bk,wk)
#define CQ       1        // c_q = dot(bq,wq)
#define CQS      2        // c_qs = c_q + dot(uq,bx)
#define U_OFF    16       // u  = wk@Wk            (300)
#define UQ_OFF   320      // uq = wq@Wq            (300)
#define UQWX_OFF 640      // uqWx = Wx^T @ uq      (300)
#define BC_OFF   960      // bc = Wp@bk + bp       (300)
#define WXT_OFF  2048     // WxT[e*300+i] = Wx[i,e]   (90000)
#define WCT_OFF  92160    // WcT[e*300+i] = (Wp@Wk)[i,e] (90000)
#define QS_OFF   182272   // qs[b]                 (512)
#define X_OFF    184320   // X  [b*300+i]          (153600)
#define XN_OFF   337920   // XN [b*300+i]          (153600)
#define M_OFF    491520   // M  [b*300+i]          (153600)
#define KS_OFF   645120   // ks [b*512+s]          (262144)
#define EU_OFF   907264   // eu[v] = dot(emb[v],u) (50000)
#define E16_OFF  958464   // emb16: 50000 x 300 half (600B/row)

#define FMA4(acc, s, v) { acc.x += (s)*(v).x; acc.y += (s)*(v).y; \
                          acc.z += (s)*(v).z; acc.w += (s)*(v).w; }

__device__ __forceinline__ float fast_exp_tanh(float z) {
    const float t = __expf(2.0f * z);
    const float th = 1.0f - 2.0f / (t + 1.0f);
    return __expf(th);
}

// ---------------------------------------------------------------------------
// pre1: blocks 0..99 WcT (transposed store), block 100: u,c_k, block 101:
// uq,c_q,bc. 102 x 1024.
// ---------------------------------------------------------------------------
__global__ __launch_bounds__(1024) void pre1(
    const float* __restrict__ Wk, const float* __restrict__ bk,
    const float* __restrict__ Wq, const float* __restrict__ bq,
    const float* __restrict__ w_mlp,
    const float* __restrict__ Wp, const float* __restrict__ bp,
    float* __restrict__ ws)
{
    const int blk  = blockIdx.x;
    const int tid  = threadIdx.x;
    const int wv   = tid >> 6;
    const int lane = tid & 63;
    __shared__ __align__(16) float buf[16 * 304 * 3 + 3 * 304];
    __shared__ float red[16];

    if (blk < 100) {
        const int i0 = blk * 3;
        float* sWp = buf + 16 * 304 * 3;
        for (int r = tid; r < 3 * DD; r += 1024)
            sWp[(r / DD) * 304 + (r % DD)] = Wp[i0 * DD + r];
        __syncthreads();

        float4 a00{0,0,0,0}, a01{0,0,0,0}, a10{0,0,0,0},
               a11{0,0,0,0}, a20{0,0,0,0}, a21{0,0,0,0};
        for (int e = wv; e < DD; e += 16) {
            const float4* kr = (const float4*)(Wk + e * DD);
            const float4 k0 = kr[lane];
            const float p0 = sWp[e], p1 = sWp[304 + e], p2 = sWp[608 + e];
            FMA4(a00, p0, k0); FMA4(a10, p1, k0); FMA4(a20, p2, k0);
            if (lane < 11) {
                const float4 k1 = kr[64 + lane];
                FMA4(a01, p0, k1); FMA4(a11, p1, k1); FMA4(a21, p2, k1);
            }
        }
        float4* p0r = (float4*)(buf + (wv * 3 + 0) * 304);
        float4* p1r = (float4*)(buf + (wv * 3 + 1) * 304);
        float4* p2r = (float4*)(buf + (wv * 3 + 2) * 304);
        p0r[lane] = a00; p1r[lane] = a10; p2r[lane] = a20;
        if (lane < 11) { p0r[64+lane] = a01; p1r[64+lane] = a11; p2r[64+lane] = a21; }
        __syncthreads();
        if (tid < DD) {
            #pragma unroll
            for (int r = 0; r < 3; ++r) {
                float s = 0.f;
                for (int w = 0; w < 16; ++w) s += buf[(w * 3 + r) * 304 + tid];
                ws[WCT_OFF + tid * DD + i0 + r] = s;   // transposed
            }
        }
        return;
    }

    const float* M  = (blk == 100) ? Wk : Wq;
    const float* vw = (blk == 100) ? w_mlp : (w_mlp + DD);
    float* s_w = buf + 16 * 304;
    float* s_b = buf + 16 * 304 + 304;
    if (tid < DD) {
        s_w[tid] = vw[tid];
        if (blk == 101) s_b[tid] = bk[tid];
    }
    __syncthreads();

    float4 a0{0,0,0,0}, a1{0,0,0,0};
    for (int e = wv; e < DD; e += 16) {
        const float4* kr = (const float4*)(M + e * DD);
        const float s = s_w[e];
        const float4 k0 = kr[lane];
        FMA4(a0, s, k0);
        if (lane < 11) { const float4 k1 = kr[64 + lane]; FMA4(a1, s, k1); }
    }
    float4* pr = (float4*)(buf + wv * 304);
    pr[lane] = a0;
    if (lane < 11) pr[64 + lane] = a1;

    float pk = 0.f;
    if (tid < DD) pk = ((blk == 100) ? bk[tid] : bq[tid]) * s_w[tid];
    #pragma unroll
    for (int off = 32; off; off >>= 1) pk += __shfl_xor(pk, off);
    if (lane == 0) red[wv] = pk;
    __syncthreads();

    const int voff = (blk == 100) ? U_OFF : UQ_OFF;
    if (tid < DD) {
        float s = 0.f;
        #pragma unroll
        for (int w = 0; w < 16; ++w) s += buf[w * 304 + tid];
        ws[voff + tid] = s;
    }
    if (tid == 0) {
        float s = 0.f;
        for (int w = 0; w < 16; ++w) s += red[w];
        ws[(blk == 100) ? CK : CQ] = s;
    }
    if (blk == 101 && tid < DD) {
        const float4* wr = (const float4*)(Wp + tid * DD);
        const float4* b4 = (const float4*)s_b;
        float a = 0.f;
        for (int j = 0; j < NF4; ++j) {
            const float4 w4 = wr[j];
            const float4 bb = b4[j];
            a += w4.x * bb.x + w4.y * bb.y + w4.z * bb.z + w4.w * bb.w;
        }
        ws[BC_OFF + tid] = a + bp[tid];
    }
}

// ---------------------------------------------------------------------------
// pre2: blocks 0..99 Wx->WxT tiles; block 100: uqWx, c_qs. 101 x 1024.
// ---------------------------------------------------------------------------
__global__ __launch_bounds__(1024) void pre2(
    const float* __restrict__ Wx, const float* __restrict__ bx,
    float* __restrict__ ws)
{
    const int blk = blockIdx.x;
    const int tid = threadIdx.x;
    __shared__ __align__(16) float tile[32][33];
    __shared__ float uq_s[304];
    __shared__ float redc[16];

    if (blk < 100) {
        const int bi = blk / 10, bj = blk % 10;
        const int ty = tid >> 5, tx = tid & 31;
        const int r = bi * 32 + ty, c = bj * 32 + tx;
        if (r < DD && c < DD) tile[ty][tx] = Wx[r * DD + c];
        __syncthreads();
        const int ro = bj * 32 + ty, co = bi * 32 + tx;
        if (ro < DD && co < DD)
            ws[WXT_OFF + ro * DD + co] = tile[tx][ty];
        return;
    }

    const int wv = tid >> 6, lane = tid & 63;
    if (tid < DD) uq_s[tid] = ws[UQ_OFF + tid];
    __syncthreads();
    if (tid < DD) {
        const float* col = Wx + tid;
        float a0 = 0.f, a1 = 0.f, a2 = 0.f, a3 = 0.f;
        for (int i = 0; i < DD; i += 4) {
            a0 += uq_s[i]     * col[(i)     * DD];
            a1 += uq_s[i + 1] * col[(i + 1) * DD];
            a2 += uq_s[i + 2] * col[(i + 2) * DD];
            a3 += uq_s[i + 3] * col[(i + 3) * DD];
        }
        ws[UQWX_OFF + tid] = (a0 + a1) + (a2 + a3);
    }
    float pq = (tid < DD) ? uq_s[tid] * bx[tid] : 0.f;
    #pragma unroll
    for (int off = 32; off; off >>= 1) pq += __shfl_xor(pq, off);
    if (lane == 0 && wv < 5) redc[wv] = pq;
    __syncthreads();
    if (tid == 0) {
        float s = 0.f;
        for (int w = 0; w < 5; ++w) s += redc[w];
        ws[CQS] = ws[CQ] + s;
    }
}

// ---------------------------------------------------------------------------
// tables: eu[v] = dot(emb[v], u) + fp16 emb copy. 512 x 1024.
// ---------------------------------------------------------------------------
__global__ __launch_bounds__(1024) void build_tables(
    const float* __restrict__ emb, float* __restrict__ ws, const int do16)
{
    const int tid  = threadIdx.x;
    const int wv   = tid >> 6;
    const int lane = tid & 63;
    __shared__ __align__(16) float u_s[DD];
    if (tid < DD) u_s[tid] = ws[U_OFF + tid];
    __syncthreads();

    const float4* u4 = (const float4*)u_s;
    const float4  q0 = u4[lane];
    const float4  q1 = (lane < 11) ? u4[64 + lane] : float4{0, 0, 0, 0};
    ushort4* e16 = (ushort4*)(ws + E16_OFF);

    const int gw     = blockIdx.x * 16 + wv;
    const int stride = gridDim.x * 16;
    for (int v = gw; v < VV; v += stride) {
        const float4* er = (const float4*)(emb + (size_t)v * DD);
        const float4 e0 = er[lane];
        float4 e1{0, 0, 0, 0};
        float a = e0.x * q0.x + e0.y * q0.y + e0.z * q0.z + e0.w * q0.w;
        if (lane < 11) {
            e1 = er[64 + lane];
            a += e1.x * q1.x + e1.y * q1.y + e1.z * q1.z + e1.w * q1.w;
        }
        #pragma unroll
        for (int off = 32; off; off >>= 1) a += __shfl_xor(a, off);
        if (lane == 0) ws[EU_OFF + v] = a;
        if (do16) {
            ushort4 h0;
            h0.x = __half_as_ushort(__float2half(e0.x));
            h0.y = __half_as_ushort(__float2half(e0.y));
            h0.z = __half_as_ushort(__float2half(e0.z));
            h0.w = __half_as_ushort(__float2half(e0.w));
            e16[(size_t)v * NF4 + lane] = h0;
            if (lane < 11) {
                ushort4 h1;
                h1.x = __half_as_ushort(__float2half(e1.x));
                h1.y = __half_as_ushort(__float2half(e1.y));
                h1.z = __half_as_ushort(__float2half(e1.z));
                h1.w = __half_as_ushort(__float2half(e1.w));
                e16[(size_t)v * NF4 + 64 + lane] = h1;
            }
        }
    }
}

// ---------------------------------------------------------------------------
// k_init: per b: len, ks row (hop-invariant), X row (aspect mean). 512x1024.
// ---------------------------------------------------------------------------
__global__ __launch_bounds__(1024) void k_init(
    const int* __restrict__ text, const int* __restrict__ asp,
    const float* __restrict__ emb, float* __restrict__ ws)
{
    const int b    = blockIdx.x;
    const int tid  = threadIdx.x;
    const int wv   = tid >> 6;
    const int lane = tid & 63;
    __shared__ float red[16];

    int t = 0;
    if (tid < SS) t = text[(size_t)b * SS + tid];
    const unsigned long long bal = __ballot(tid < SS && t != 0);
    if (lane == 0) red[wv] = (float)__popcll(bal);
    __syncthreads();

    int len = 0;
    #pragma unroll
    for (int w = 0; w < 16; ++w) len += (int)red[w];
    const float lenf = (float)len;
    const int   s0   = SS - len;

    if (tid < SS) {
        const int j = tid - s0;
        const float wg = (j >= 0) ? (1.0f - (float)j / lenf) : 1.0f;
        ws[KS_OFF + b * SS + tid] = wg * ws[EU_OFF + t] + ws[CK];
    }
    if (tid < DD) {
        float na = 0.f, a = 0.f;
        #pragma unroll
        for (int k = 0; k < 8; ++k) {
            const int idx = asp[b * 8 + k];
            na += (idx != 0) ? 1.0f : 0.0f;
            a += emb[(size_t)idx * DD + tid];
        }
        ws[X_OFF + b * DD + tid] = a / na;
    }
}

// ---------------------------------------------------------------------------
// k_gemm: out[b0+bb][i] = sum_e A[b0+bb][e]*W[e*300+i] + bias[i] (+res).
// G=4 rows/block, 128 blocks x 1024. Optional qs epilogue (A-variant):
// qs[b] = dot(A[b], uqWx) + c_qs.
// ---------------------------------------------------------------------------
__global__ __launch_bounds__(1024) void k_gemm(
    const float* __restrict__ A, const float* __restrict__ W,
    const float* __restrict__ bias, const float* __restrict__ res,
    float* __restrict__ outp, const float* __restrict__ ws,
    float* __restrict__ qs_out, const int with_qs)
{
    const int b0   = blockIdx.x * 4;
    const int tid  = threadIdx.x;
    const int wv   = tid >> 6;
    const int lane = tid & 63;
    __shared__ __align__(16) float As[4][304];
    __shared__ __align__(16) float part[3][4][304];
    __shared__ __align__(16) float uqx[304];

    for (int idx = tid; idx < 4 * DD; idx += 1024) {
        const int bb = idx / DD, e = idx - bb * DD;
        As[bb][e] = A[(b0 + bb) * DD + e];
    }
    if (with_qs && tid < DD) uqx[tid] = ws[UQWX_OFF + tid];
    __syncthreads();

    const int g = tid / 304;
    const int i = tid - g * 304;
    if (g < 3 && i < DD) {
        const int e0 = g * 100;
        float a0 = 0.f, a1 = 0.f, a2 = 0.f, a3 = 0.f;
        for (int e = e0; e < e0 + 100; e += 2) {
            const float w0 = W[e * DD + i];
            const float w1 = W[(e + 1) * DD + i];
            a0 += As[0][e] * w0 + As[0][e + 1] * w1;
            a1 += As[1][e] * w0 + As[1][e + 1] * w1;
            a2 += As[2][e] * w0 + As[2][e + 1] * w1;
            a3 += As[3][e] * w0 + As[3][e + 1] * w1;
        }
        part[g][0][i] = a0; part[g][1][i] = a1;
        part[g][2][i] = a2; part[g][3][i] = a3;
    }
    __syncthreads();

    #pragma unroll
    for (int rep = 0; rep < 2; ++rep) {
        const int j = rep * 1024 + tid;
        if (j < 4 * DD) {
            const int bb = j / DD, ii = j - bb * DD;
            float v = part[0][bb][ii] + part[1][bb][ii] + part[2][bb][ii]
                    + bias[ii];
            if (res) v += res[(b0 + bb) * DD + ii];
            outp[(b0 + bb) * DD + ii] = v;
        }
    }

    if (with_qs && wv < 4) {
        const float4* x4 = (const float4*)As[wv];
        const float4* u4 = (const float4*)uqx;
        const float4 xa = x4[lane], ua = u4[lane];
        float a = xa.x * ua.x + xa.y * ua.y + xa.z * ua.z + xa.w * ua.w;
        if (lane < 11) {
            const float4 xb = x4[64 + lane], ub = u4[64 + lane];
            a += xb.x * ub.x + xb.y * ub.y + xb.z * ub.z + xb.w * ub.w;
        }
        #pragma unroll
        for (int off = 32; off; off >>= 1) a += __shfl_xor(a, off);
        if (lane == 0) qs_out[b0 + wv] = a + ws[CQS];
    }
}

// ---------------------------------------------------------------------------
// k_attn: per b: cw computed wave-locally (no shfl, no cw LDS),
// m-gather from fp16 table, normalized M row out. 512 x 1024, 2 barriers.
// ---------------------------------------------------------------------------
__global__ __launch_bounds__(1024) void k_attn(
    const int* __restrict__ text, const float* __restrict__ emb,
    float* __restrict__ ws, const int use16)
{
    const int b    = blockIdx.x;
    const int tid  = threadIdx.x;
    const int wv   = tid >> 6;
    const int lane = tid & 63;
    __shared__ int   ti[SS];
    __shared__ float red[16];
    __shared__ float red2[16];
    __shared__ __align__(16) float mpart[16][304];

    int t = 0;
    if (tid < SS) { t = text[(size_t)b * SS + tid]; ti[tid] = t; }
    const unsigned long long bal = __ballot(tid < SS && t != 0);
    if (lane == 0) red[wv] = (float)__popcll(bal);
    __syncthreads();

    int len = 0;
    #pragma unroll
    for (int w = 0; w < 16; ++w) len += (int)red[w];
    const float lenf = (float)len;
    const int   s0   = SS - len;

    const float qs = ws[QS_OFF + b];
    const float* ksrow = ws + KS_OFF + b * SS;
    const ushort4* e16 = (const ushort4*)(ws + E16_OFF);

    float4 acc{0, 0, 0, 0}, accb{0, 0, 0, 0};
    float spw = 0.f;
    const int start = s0 + ((wv - s0) & 15);

    if (use16) {
        #pragma unroll 4
        for (int s = start; s < SS; s += 16) {
            const int row = ti[s];
            const float p = fast_exp_tanh(ksrow[s] + qs);
            spw += p;
            const float c = p * (1.0f - (float)(s - s0) / lenf);
            const ushort4* r16 = e16 + (size_t)row * NF4;
            const ushort4 h0 = r16[lane];
            const float2 f0 = __half22float2(*(const __half2*)&h0.x);
            const float2 f1 = __half22float2(*(const __half2*)&h0.z);
            acc.x += c * f0.x; acc.y += c * f0.y;
            acc.z += c * f1.x; acc.w += c * f1.y;
            if (lane < 11) {
                const ushort4 h1 = r16[64 + lane];
                const float2 g0 = __half22float2(*(const __half2*)&h1.x);
                const float2 g1 = __half22float2(*(const __half2*)&h1.z);
                accb.x += c * g0.x; accb.y += c * g0.y;
                accb.z += c * g1.x; accb.w += c * g1.y;
            }
        }
    } else {
        #pragma unroll 4
        for (int s = start; s < SS; s += 16) {
            const int row = ti[s];
            const float p = fast_exp_tanh(ksrow[s] + qs);
            spw += p;
            const float c = p * (1.0f - (float)(s - s0) / lenf);
            const float4* er = (const float4*)(emb + (size_t)row * DD);
            const float4 f = er[lane];
            acc.x += c * f.x; acc.y += c * f.y;
            acc.z += c * f.z; acc.w += c * f.w;
            if (lane < 11) {
                const float4 f1 = er[64 + lane];
                accb.x += c * f1.x; accb.y += c * f1.y;
                accb.z += c * f1.z; accb.w += c * f1.w;
            }
        }
    }
    // pad positions (s<s0) are excluded by construction; exp(tanh(ks_pad+qs))
    // for pads never enters spw -> matches softmax over... NOTE: reference
    // softmax includes pad positions! Their p = exp(tanh(c_k+qs)) with
    // emb[0]=0 contributes to the denominator AND cw*emb adds 0 to m.
    // Add the pad contribution to spw analytically: s0 pads, all same p.
    if (wv == 0 && lane == 0 && s0 > 0) {
        // handled below via red2[15]+... store pad term in red2 slot via wave0
    }
    if (lane == 0) red2[wv] = spw;
    ((float4*)&mpart[wv][0])[lane] = acc;
    if (lane < 11) ((float4*)&mpart[wv][0])[64 + lane] = accb;
    __syncthreads();

    if (tid < DD) {
        const float pad_p = fast_exp_tanh(ksrow[0] + qs); // s<s0: ks=c_k uniform
        float sumP = (s0 > 0) ? (float)s0 * pad_p : 0.f;
        #pragma unroll
        for (int w = 0; w < 16; ++w) sumP += red2[w];
        float mm = 0.f;
        #pragma unroll
        for (int w = 0; w < 16; ++w) mm += mpart[w][tid];
        ws[M_OFF + b * DD + tid] = mm / sumP;
    }
}

// ---------------------------------------------------------------------------
// k_out: out[b,p] = dot(Wd[p], X[b]) + bd[p]. 512 x 256.
// ---------------------------------------------------------------------------
__global__ __launch_bounds__(256) void k_out(
    const float* __restrict__ Wd, const float* __restrict__ bd,
    const float* __restrict__ ws, float* __restrict__ out)
{
    const int b    = blockIdx.x;
    const int tid  = threadIdx.x;
    const int wv   = tid >> 6;
    const int lane = tid & 63;
    if (wv >= 3) return;
    const float4* wr = (const float4*)(Wd + wv * DD);
    const float4* x4 = (const float4*)(ws + X_OFF + b * DD);
    const float4 w0 = wr[lane];
    const float4 v0 = x4[lane];
    float a = w0.x * v0.x + w0.y * v0.y + w0.z * v0.z + w0.w * v0.w;
    if (lane < 11) {
        const float4 w1 = wr[64 + lane];
        const float4 v1 = x4[64 + lane];
        a += w1.x * v1.x + w1.y * v1.y + w1.z * v1.z + w1.w * v1.w;
    }
    #pragma unroll
    for (int off = 32; off; off >>= 1) a += __shfl_xor(a, off);
    if (lane == 0) out[b * 3 + wv] = a + bd[wv];
}

extern "C" void kernel_launch(void* const* d_in, const int* in_sizes, int n_in,
                              void* d_out, int out_size, void* d_ws, size_t ws_size,
                              hipStream_t stream)
{
    const int*   text = (const int*)d_in[0];
    const int*   asp  = (const int*)d_in[1];
    const float* emb  = (const float*)d_in[2];
    const float* Wx   = (const float*)d_in[3];
    const float* bx   = (const float*)d_in[4];
    const float* Wk   = (const float*)d_in[5];
    const float* bk   = (const float*)d_in[6];
    const float* Wq   = (const float*)d_in[7];
    const float* bq   = (const float*)d_in[8];
    const float* wm   = (const float*)d_in[9];
    const float* Wp   = (const float*)d_in[10];
    const float* bp   = (const float*)d_in[11];
    const float* Wd   = (const float*)d_in[12];
    const float* bd   = (const float*)d_in[13];
    float* out = (float*)d_out;
    float* ws  = (float*)d_ws;

    const size_t need = (size_t)E16_OFF * 4 + (size_t)VV * DD * 2;
    const int use16 = (ws_size >= need) ? 1 : 0;

    float* X  = ws + X_OFF;
    float* XN = ws + XN_OFF;
    float* M  = ws + M_OFF;
    float* QS = ws + QS_OFF;
    const float* WXT = ws + WXT_OFF;
    const float* WCT = ws + WCT_OFF;
    const float* BC  = ws + BC_OFF;

    pre1<<<102, 1024, 0, stream>>>(Wk, bk, Wq, bq, wm, Wp, bp, ws);
    pre2<<<101, 1024, 0, stream>>>(Wx, bx, ws);
    build_tables<<<512, 1024, 0, stream>>>(emb, ws, use16);
    k_init<<<512, 1024, 0, stream>>>(text, asp, emb, ws);
    for (int hop = 0; hop < 3; ++hop) {
        k_gemm<<<128, 1024, 0, stream>>>(X, WXT, bx, nullptr, XN, ws, QS, 1);
        k_attn<<<512, 1024, 0, stream>>>(text, emb, ws, use16);
        k_gemm<<<128, 1024, 0, stream>>>(M, WCT, BC, XN, X, ws, nullptr, 0);
    }
    k_out<<<512, 256, 0, stream>>>(Wd, bd, ws, out);
}

// Round 7
// 276.205 us; speedup vs baseline: 3.1500x; 1.3823x over previous
//
#include <hip/hip_runtime.h>
#include <hip/hip_fp16.h>

#define DD 300
#define SS 512
#define VV 50000
#define NF4 75
#define NCH 8          // chunks per batch row in k_attn

// Workspace layout (float index):
#define CK       0
#define CQ       1
#define CQS      2
#define U_OFF    16       // u  = wk@Wk
#define UQ_OFF   320      // uq = wq@Wq
#define UQWX_OFF 640      // uqWx = Wx^T @ uq
#define BC_OFF   960      // bc = Wp@bk + bp
#define WXT_OFF  2048     // WxT[e*300+i] = Wx[i,e]
#define WCT_OFF  92160    // WcT[e*300+i] = (Wp@Wk)[i,e]
#define QS_OFF   182272   // qs[b]
#define S0_OFF   182784   // s0[b] (int)
#define M_OFF    183296   // M[b*304+j] atomic accumulator
#define X0_OFF   338944   // aspect means
#define XN_OFF   492544   // XN[b*300+i]
#define KS_OFF   646144   // ks[b*512+s]
#define SP_OFF   908288   // sumP[b] atomic accumulator
#define EU_OFF   908800   // eu[v]
#define E16_OFF  958848   // fp16 emb copy (600 B/row)

#define FMA4(acc, s, v) { acc.x += (s)*(v).x; acc.y += (s)*(v).y; \
                          acc.z += (s)*(v).z; acc.w += (s)*(v).w; }

__device__ __forceinline__ float fast_exp_tanh(float z) {
    const float t = __expf(2.0f * z);
    const float th = 1.0f - 2.0f / (t + 1.0f);
    return __expf(th);
}

// ---------------------------------------------------------------------------
// pre1: blocks 0..99 WcT rows (transposed store); blk 100: u,c_k;
// blk 101: uq,c_q,bc (bc via wave-per-row reduce). 102 x 1024.
// ---------------------------------------------------------------------------
__global__ __launch_bounds__(1024) void pre1(
    const float* __restrict__ Wk, const float* __restrict__ bk,
    const float* __restrict__ Wq, const float* __restrict__ bq,
    const float* __restrict__ w_mlp,
    const float* __restrict__ Wp, const float* __restrict__ bp,
    float* __restrict__ ws)
{
    const int blk  = blockIdx.x;
    const int tid  = threadIdx.x;
    const int wv   = tid >> 6;
    const int lane = tid & 63;
    __shared__ __align__(16) float buf[16 * 304 * 3 + 3 * 304];
    __shared__ float red[16];

    if (blk < 100) {
        const int i0 = blk * 3;
        float* sWp = buf + 16 * 304 * 3;
        for (int r = tid; r < 3 * DD; r += 1024)
            sWp[(r / DD) * 304 + (r % DD)] = Wp[i0 * DD + r];
        __syncthreads();

        float4 a00{0,0,0,0}, a01{0,0,0,0}, a10{0,0,0,0},
               a11{0,0,0,0}, a20{0,0,0,0}, a21{0,0,0,0};
        for (int e = wv; e < DD; e += 16) {
            const float4* kr = (const float4*)(Wk + e * DD);
            const float4 k0 = kr[lane];
            const float p0 = sWp[e], p1 = sWp[304 + e], p2 = sWp[608 + e];
            FMA4(a00, p0, k0); FMA4(a10, p1, k0); FMA4(a20, p2, k0);
            if (lane < 11) {
                const float4 k1 = kr[64 + lane];
                FMA4(a01, p0, k1); FMA4(a11, p1, k1); FMA4(a21, p2, k1);
            }
        }
        float4* p0r = (float4*)(buf + (wv * 3 + 0) * 304);
        float4* p1r = (float4*)(buf + (wv * 3 + 1) * 304);
        float4* p2r = (float4*)(buf + (wv * 3 + 2) * 304);
        p0r[lane] = a00; p1r[lane] = a10; p2r[lane] = a20;
        if (lane < 11) { p0r[64+lane] = a01; p1r[64+lane] = a11; p2r[64+lane] = a21; }
        __syncthreads();
        if (tid < DD) {
            #pragma unroll
            for (int r = 0; r < 3; ++r) {
                float s = 0.f;
                for (int w = 0; w < 16; ++w) s += buf[(w * 3 + r) * 304 + tid];
                ws[WCT_OFF + tid * DD + i0 + r] = s;   // transposed
            }
        }
        return;
    }

    const float* M  = (blk == 100) ? Wk : Wq;
    const float* vw = (blk == 100) ? w_mlp : (w_mlp + DD);
    float* s_w = buf + 16 * 304;
    float* s_b = buf + 16 * 304 + 304;
    if (tid < DD) {
        s_w[tid] = vw[tid];
        if (blk == 101) s_b[tid] = bk[tid];
    }
    __syncthreads();

    float4 a0{0,0,0,0}, a1{0,0,0,0};
    for (int e = wv; e < DD; e += 16) {
        const float4* kr = (const float4*)(M + e * DD);
        const float s = s_w[e];
        const float4 k0 = kr[lane];
        FMA4(a0, s, k0);
        if (lane < 11) { const float4 k1 = kr[64 + lane]; FMA4(a1, s, k1); }
    }
    float4* pr = (float4*)(buf + wv * 304);
    pr[lane] = a0;
    if (lane < 11) pr[64 + lane] = a1;

    float pk = 0.f;
    if (tid < DD) pk = ((blk == 100) ? bk[tid] : bq[tid]) * s_w[tid];
    #pragma unroll
    for (int off = 32; off; off >>= 1) pk += __shfl_xor(pk, off);
    if (lane == 0) red[wv] = pk;
    __syncthreads();

    const int voff = (blk == 100) ? U_OFF : UQ_OFF;
    if (tid < DD) {
        float s = 0.f;
        #pragma unroll
        for (int w = 0; w < 16; ++w) s += buf[w * 304 + tid];
        ws[voff + tid] = s;
    }
    if (tid == 0) {
        float s = 0.f;
        for (int w = 0; w < 16; ++w) s += red[w];
        ws[(blk == 100) ? CK : CQ] = s;
    }
    if (blk == 101) {
        // bc[i] = dot(Wp[i,:], bk) + bp[i] : wave per row, coalesced
        const float4* b4 = (const float4*)s_b;
        const float4 k0 = b4[lane];
        const float4 k1 = (lane < 11) ? b4[64 + lane] : float4{0, 0, 0, 0};
        for (int i2 = wv; i2 < DD; i2 += 16) {
            const float4* wr = (const float4*)(Wp + i2 * DD);
            const float4 w0 = wr[lane];
            float a = w0.x * k0.x + w0.y * k0.y + w0.z * k0.z + w0.w * k0.w;
            if (lane < 11) {
                const float4 w1 = wr[64 + lane];
                a += w1.x * k1.x + w1.y * k1.y + w1.z * k1.z + w1.w * k1.w;
            }
            #pragma unroll
            for (int off = 32; off; off >>= 1) a += __shfl_xor(a, off);
            if (lane == 0) ws[BC_OFF + i2] = a + bp[i2];
        }
    }
}

// ---------------------------------------------------------------------------
// pre2: blocks 0..99 Wx->WxT tiles; blk 100: uqWx (row-major accumulate),
// c_qs. 101 x 1024.
// ---------------------------------------------------------------------------
__global__ __launch_bounds__(1024) void pre2(
    const float* __restrict__ Wx, const float* __restrict__ bx,
    float* __restrict__ ws)
{
    const int blk = blockIdx.x;
    const int tid = threadIdx.x;
    __shared__ __align__(16) float tile[32][33];
    __shared__ __align__(16) float part2[16][304];
    __shared__ float uq_s[304];
    __shared__ float redc[16];

    if (blk < 100) {
        const int bi = blk / 10, bj = blk % 10;
        const int ty = tid >> 5, tx = tid & 31;
        const int r = bi * 32 + ty, c = bj * 32 + tx;
        if (r < DD && c < DD) tile[ty][tx] = Wx[r * DD + c];
        __syncthreads();
        const int ro = bj * 32 + ty, co = bi * 32 + tx;
        if (ro < DD && co < DD)
            ws[WXT_OFF + ro * DD + co] = tile[tx][ty];
        return;
    }

    const int wv = tid >> 6, lane = tid & 63;
    if (tid < DD) uq_s[tid] = ws[UQ_OFF + tid];
    __syncthreads();

    float4 a0{0,0,0,0}, a1{0,0,0,0};
    for (int i = wv; i < DD; i += 16) {
        const float s = uq_s[i];
        const float4* xr = (const float4*)(Wx + i * DD);
        FMA4(a0, s, xr[lane]);
        if (lane < 11) { const float4 x1 = xr[64 + lane]; FMA4(a1, s, x1); }
    }
    ((float4*)&part2[wv][0])[lane] = a0;
    if (lane < 11) ((float4*)&part2[wv][0])[64 + lane] = a1;

    float pq = (tid < DD) ? uq_s[tid] * bx[tid] : 0.f;
    #pragma unroll
    for (int off = 32; off; off >>= 1) pq += __shfl_xor(pq, off);
    if (lane == 0) redc[wv] = pq;
    __syncthreads();

    if (tid < DD) {
        float s = 0.f;
        #pragma unroll
        for (int w = 0; w < 16; ++w) s += part2[w][tid];
        ws[UQWX_OFF + tid] = s;
    }
    if (tid == 0) {
        float s = 0.f;
        for (int w = 0; w < 16; ++w) s += redc[w];
        ws[CQS] = ws[CQ] + s;
    }
}

// ---------------------------------------------------------------------------
// tables: eu[v] = dot(emb[v], u) + fp16 emb copy. 512 x 1024.
// ---------------------------------------------------------------------------
__global__ __launch_bounds__(1024) void build_tables(
    const float* __restrict__ emb, float* __restrict__ ws, const int do16)
{
    const int tid  = threadIdx.x;
    const int wv   = tid >> 6;
    const int lane = tid & 63;
    __shared__ __align__(16) float u_s[DD];
    if (tid < DD) u_s[tid] = ws[U_OFF + tid];
    __syncthreads();

    const float4* u4 = (const float4*)u_s;
    const float4  q0 = u4[lane];
    const float4  q1 = (lane < 11) ? u4[64 + lane] : float4{0, 0, 0, 0};
    ushort4* e16 = (ushort4*)(ws + E16_OFF);

    const int gw     = blockIdx.x * 16 + wv;
    const int stride = gridDim.x * 16;
    for (int v = gw; v < VV; v += stride) {
        const float4* er = (const float4*)(emb + (size_t)v * DD);
        const float4 e0 = er[lane];
        float4 e1{0, 0, 0, 0};
        float a = e0.x * q0.x + e0.y * q0.y + e0.z * q0.z + e0.w * q0.w;
        if (lane < 11) {
            e1 = er[64 + lane];
            a += e1.x * q1.x + e1.y * q1.y + e1.z * q1.z + e1.w * q1.w;
        }
        #pragma unroll
        for (int off = 32; off; off >>= 1) a += __shfl_xor(a, off);
        if (lane == 0) ws[EU_OFF + v] = a;
        if (do16) {
            ushort4 h0;
            h0.x = __half_as_ushort(__float2half(e0.x));
            h0.y = __half_as_ushort(__float2half(e0.y));
            h0.z = __half_as_ushort(__float2half(e0.z));
            h0.w = __half_as_ushort(__float2half(e0.w));
            e16[(size_t)v * NF4 + lane] = h0;
            if (lane < 11) {
                ushort4 h1;
                h1.x = __half_as_ushort(__float2half(e1.x));
                h1.y = __half_as_ushort(__float2half(e1.y));
                h1.z = __half_as_ushort(__float2half(e1.z));
                h1.w = __half_as_ushort(__float2half(e1.w));
                e16[(size_t)v * NF4 + 64 + lane] = h1;
            }
        }
    }
}

// ---------------------------------------------------------------------------
// k_init: per b: s0, ks row (hop-invariant), X0 (aspect mean). 512 x 512.
// ---------------------------------------------------------------------------
__global__ __launch_bounds__(512) void k_init(
    const int* __restrict__ text, const int* __restrict__ asp,
    const float* __restrict__ emb, float* __restrict__ ws)
{
    const int b    = blockIdx.x;
    const int tid  = threadIdx.x;
    const int wv   = tid >> 6;
    const int lane = tid & 63;
    __shared__ float red[8];

    const int t = text[b * SS + tid];
    const unsigned long long bal = __ballot(t != 0);
    if (lane == 0) red[wv] = (float)__popcll(bal);
    __syncthreads();

    int len = 0;
    #pragma unroll
    for (int w = 0; w < 8; ++w) len += (int)red[w];
    const int   s0   = SS - len;
    const float lenf = (float)len;

    {
        const int j = tid - s0;
        const float wg = (j >= 0) ? (1.0f - (float)j / lenf) : 1.0f;
        ws[KS_OFF + b * SS + tid] = wg * ws[EU_OFF + t] + ws[CK];
    }
    if (tid == 0) ((int*)(ws + S0_OFF))[b] = s0;
    if (tid < DD) {
        float na = 0.f, a = 0.f;
        #pragma unroll
        for (int k = 0; k < 8; ++k) {
            const int idx = asp[b * 8 + k];
            na += (idx != 0) ? 1.0f : 0.0f;
            a += emb[(size_t)idx * DD + tid];
        }
        ws[X0_OFF + b * DD + tid] = a / na;
    }
}

// ---------------------------------------------------------------------------
// k_attn: 4096 blocks (b x 8 chunks) x 256 threads. Softmax coeffs hoisted
// to a per-chunk LDS stage; gather loop = pure prefetched loads + FMA.
// Partials accumulated with fp32 atomics into M[b], SP[b].
// ---------------------------------------------------------------------------
__global__ __launch_bounds__(256) void k_attn(
    const int* __restrict__ text, const float* __restrict__ emb,
    float* __restrict__ ws, const int use16)
{
    const int blk  = blockIdx.x;
    const int b    = blk >> 3;
    const int c    = blk & 7;
    const int tid  = threadIdx.x;
    const int wv   = tid >> 6;
    const int lane = tid & 63;

    const int s0  = ((const int*)(ws + S0_OFF))[b];
    const int len = SS - s0;
    const int q   = (len + NCH - 1) >> 3;
    const int sb  = s0 + c * q;
    if (sb >= SS) return;
    const int se = min(sb + q, SS);
    const int n  = se - sb;                 // 1..64 rows in this chunk

    __shared__ int   stok[64];
    __shared__ float scw[64];
    __shared__ float sps[64];
    __shared__ __align__(16) float mpart[4][304];

    const float qs   = ws[QS_OFF + b];
    const float lenf = (float)len;
    if (tid < n) {
        const int s = sb + tid;
        stok[tid] = text[b * SS + s];
        const float p = fast_exp_tanh(ws[KS_OFF + b * SS + s] + qs);
        sps[tid] = p;
        scw[tid] = p * (1.0f - (float)(s - s0) / lenf);
    }
    __syncthreads();

    if (wv == 0) {
        float v = (lane < n) ? sps[lane] : 0.f;
        #pragma unroll
        for (int off = 32; off; off >>= 1) v += __shfl_xor(v, off);
        if (lane == 0) atomicAdd(ws + SP_OFF + b, v);
    }

    const int qw = (q + 3) >> 2;            // rows per wave (<=16)
    const int r0 = wv * qw;
    const int r1 = min(r0 + qw, n);

    float4 acc{0, 0, 0, 0}, accb{0, 0, 0, 0};

    if (use16) {
        const ushort4* e16 = (const ushort4*)(ws + E16_OFF);
        ushort4 ca[4] = {}, cb[4] = {};
        #pragma unroll
        for (int k = 0; k < 4; ++k) {
            const int r = r0 + k;
            if (r < r1) {
                const ushort4* rp = e16 + (size_t)stok[r] * NF4;
                ca[k] = rp[lane];
                if (lane < 11) cb[k] = rp[64 + lane];
            }
        }
        for (int base = r0; base < r1; base += 4) {
            ushort4 na[4] = {}, nb[4] = {};
            #pragma unroll
            for (int k = 0; k < 4; ++k) {
                const int rn = base + 4 + k;
                if (rn < r1) {
                    const ushort4* rp = e16 + (size_t)stok[rn] * NF4;
                    na[k] = rp[lane];
                    if (lane < 11) nb[k] = rp[64 + lane];
                }
            }
            #pragma unroll
            for (int k = 0; k < 4; ++k) {
                const int r = base + k;
                if (r < r1) {
                    const float cc = scw[r];
                    const float2 f0 = __half22float2(*(const __half2*)&ca[k].x);
                    const float2 f1 = __half22float2(*(const __half2*)&ca[k].z);
                    acc.x += cc * f0.x; acc.y += cc * f0.y;
                    acc.z += cc * f1.x; acc.w += cc * f1.y;
                    if (lane < 11) {
                        const float2 g0 = __half22float2(*(const __half2*)&cb[k].x);
                        const float2 g1 = __half22float2(*(const __half2*)&cb[k].z);
                        accb.x += cc * g0.x; accb.y += cc * g0.y;
                        accb.z += cc * g1.x; accb.w += cc * g1.y;
                    }
                }
            }
            #pragma unroll
            for (int k = 0; k < 4; ++k) { ca[k] = na[k]; cb[k] = nb[k]; }
        }
    } else {
        for (int r = r0; r < r1; ++r) {
            const float cc = scw[r];
            const float4* er = (const float4*)(emb + (size_t)stok[r] * DD);
            const float4 f = er[lane];
            acc.x += cc * f.x; acc.y += cc * f.y;
            acc.z += cc * f.z; acc.w += cc * f.w;
            if (lane < 11) {
                const float4 f1 = er[64 + lane];
                accb.x += cc * f1.x; accb.y += cc * f1.y;
                accb.z += cc * f1.z; accb.w += cc * f1.w;
            }
        }
    }
    ((float4*)&mpart[wv][0])[lane] = acc;
    if (lane < 11) ((float4*)&mpart[wv][0])[64 + lane] = accb;
    __syncthreads();

    for (int j = tid; j < DD; j += 256) {
        const float v = mpart[0][j] + mpart[1][j] + mpart[2][j] + mpart[3][j];
        atomicAdd(ws + M_OFF + b * 304 + j, v);
    }
}

// ---------------------------------------------------------------------------
// k_gemm: 256 blocks x 1024 threads, 2 batch rows per block.
// mode 0: XN = X0@WxT+bx, qs; zero M/SP.
// mode 1: X = (M/sumP)@WcT+bc+XN; XN = X@WxT+bx; qs; zero M/SP.
// mode 2: X = (M/sumP)@WcT+bc+XN; out = X@Wd^T+bd.
// ---------------------------------------------------------------------------
__global__ __launch_bounds__(1024) void k_gemm(
    float* __restrict__ ws, const float* __restrict__ bx,
    const float* __restrict__ Wd, const float* __restrict__ bd,
    float* __restrict__ out, const int mode)
{
    const int b0   = blockIdx.x * 2;
    const int tid  = threadIdx.x;
    const int wv   = tid >> 6;
    const int lane = tid & 63;
    __shared__ __align__(16) float As[2][304];
    __shared__ __align__(16) float part[3][2][304];
    __shared__ __align__(16) float uqx[304];
    __shared__ float isp[2];

    if (mode == 0) {
        for (int idx = tid; idx < 2 * DD; idx += 1024) {
            const int bb = idx / DD, e = idx - bb * DD;
            As[bb][e] = ws[X0_OFF + (b0 + bb) * DD + e];
        }
    } else {
        if (tid < 2) {
            const int b = b0 + tid;
            const int s0 = ((const int*)(ws + S0_OFF))[b];
            const float qs = ws[QS_OFF + b];
            float sp = ws[SP_OFF + b];
            if (s0 > 0) sp += (float)s0 * fast_exp_tanh(ws[CK] + qs);
            isp[tid] = 1.0f / sp;
        }
        __syncthreads();
        for (int idx = tid; idx < 2 * DD; idx += 1024) {
            const int bb = idx / DD, e = idx - bb * DD;
            As[bb][e] = ws[M_OFF + (b0 + bb) * 304 + e] * isp[bb];
        }
    }
    if (tid < DD) uqx[tid] = ws[UQWX_OFF + tid];
    // zero M/SP for the next k_attn (modes 0 and 1)
    if (mode != 2) {
        for (int idx = tid; idx < 2 * 304; idx += 1024) {
            const int bb = idx / 304, e = idx - bb * 304;
            ws[M_OFF + (b0 + bb) * 304 + e] = 0.f;
        }
        if (tid < 2) ws[SP_OFF + b0 + tid] = 0.f;
    }
    __syncthreads();

    const int g = tid / 304;
    const int i = tid - g * 304;
    const bool act = (g < 3) && (i < DD);

    if (mode != 0) {
        // GEMM1: X = As @ WcT + bc + XN  -> back into As
        if (act) {
            const float* W = ws + WCT_OFF;
            const int e0 = g * 100;
            float a0 = 0.f, a1 = 0.f;
            for (int e = e0; e < e0 + 100; e += 2) {
                const float w0 = W[e * DD + i];
                const float w1 = W[(e + 1) * DD + i];
                a0 += As[0][e] * w0 + As[0][e + 1] * w1;
                a1 += As[1][e] * w0 + As[1][e + 1] * w1;
            }
            part[g][0][i] = a0; part[g][1][i] = a1;
        }
        __syncthreads();
        for (int idx = tid; idx < 2 * DD; idx += 1024) {
            const int bb = idx / DD, e = idx - bb * DD;
            As[bb][e] = part[0][bb][e] + part[1][bb][e] + part[2][bb][e]
                      + ws[BC_OFF + e] + ws[XN_OFF + (b0 + bb) * DD + e];
        }
        __syncthreads();
    }

    if (mode == 2) {
        if (wv < 6) {
            const int bb = wv / 3, p = wv - bb * 3;
            const float4* wr = (const float4*)(Wd + p * DD);
            const float4* x4 = (const float4*)As[bb];
            const float4 w0 = wr[lane], v0 = x4[lane];
            float a = w0.x * v0.x + w0.y * v0.y + w0.z * v0.z + w0.w * v0.w;
            if (lane < 11) {
                const float4 w1 = wr[64 + lane], v1 = x4[64 + lane];
                a += w1.x * v1.x + w1.y * v1.y + w1.z * v1.z + w1.w * v1.w;
            }
            #pragma unroll
            for (int off = 32; off; off >>= 1) a += __shfl_xor(a, off);
            if (lane == 0) out[(b0 + bb) * 3 + p] = a + bd[p];
        }
        return;
    }

    // GEMM2: XN = As @ WxT + bx
    if (act) {
        const float* W = ws + WXT_OFF;
        const int e0 = g * 100;
        float a0 = 0.f, a1 = 0.f;
        for (int e = e0; e < e0 + 100; e += 2) {
            const float w0 = W[e * DD + i];
            const float w1 = W[(e + 1) * DD + i];
            a0 += As[0][e] * w0 + As[0][e + 1] * w1;
            a1 += As[1][e] * w0 + As[1][e + 1] * w1;
        }
        part[g][0][i] = a0; part[g][1][i] = a1;
    }
    __syncthreads();
    for (int idx = tid; idx < 2 * DD; idx += 1024) {
        const int bb = idx / DD, e = idx - bb * DD;
        ws[XN_OFF + (b0 + bb) * DD + e] =
            part[0][bb][e] + part[1][bb][e] + part[2][bb][e] + bx[e];
    }
    // qs epilogue
    if (wv < 2) {
        const float4* x4 = (const float4*)As[wv];
        const float4* u4 = (const float4*)uqx;
        const float4 xa = x4[lane], ua = u4[lane];
        float a = xa.x * ua.x + xa.y * ua.y + xa.z * ua.z + xa.w * ua.w;
        if (lane < 11) {
            const float4 xb = x4[64 + lane], ub = u4[64 + lane];
            a += xb.x * ub.x + xb.y * ub.y + xb.z * ub.z + xb.w * ub.w;
        }
        #pragma unroll
        for (int off = 32; off; off >>= 1) a += __shfl_xor(a, off);
        if (lane == 0) ws[QS_OFF + b0 + wv] = a + ws[CQS];
    }
}

extern "C" void kernel_launch(void* const* d_in, const int* in_sizes, int n_in,
                              void* d_out, int out_size, void* d_ws, size_t ws_size,
                              hipStream_t stream)
{
    const int*   text = (const int*)d_in[0];
    const int*   asp  = (const int*)d_in[1];
    const float* emb  = (const float*)d_in[2];
    const float* Wx   = (const float*)d_in[3];
    const float* bx   = (const float*)d_in[4];
    const float* Wk   = (const float*)d_in[5];
    const float* bk   = (const float*)d_in[6];
    const float* Wq   = (const float*)d_in[7];
    const float* bq   = (const float*)d_in[8];
    const float* wm   = (const float*)d_in[9];
    const float* Wp   = (const float*)d_in[10];
    const float* bp   = (const float*)d_in[11];
    const float* Wd   = (const float*)d_in[12];
    const float* bd   = (const float*)d_in[13];
    float* out = (float*)d_out;
    float* ws  = (float*)d_ws;

    const size_t need = (size_t)E16_OFF * 4 + (size_t)VV * DD * 2;
    const int use16 = (ws_size >= need) ? 1 : 0;

    pre1<<<102, 1024, 0, stream>>>(Wk, bk, Wq, bq, wm, Wp, bp, ws);
    pre2<<<101, 1024, 0, stream>>>(Wx, bx, ws);
    build_tables<<<512, 1024, 0, stream>>>(emb, ws, use16);
    k_init<<<512, 512, 0, stream>>>(text, asp, emb, ws);
    k_gemm<<<256, 1024, 0, stream>>>(ws, bx, Wd, bd, out, 0);
    for (int hop = 0; hop < 3; ++hop) {
        k_attn<<<512 * NCH, 256, 0, stream>>>(text, emb, ws, use16);
        k_gemm<<<256, 1024, 0, stream>>>(ws, bx, Wd, bd, out, (hop < 2) ? 1 : 2);
    }
}